// Round 4
// baseline (249.396 us; speedup 1.0000x reference)
//
#include <hip/hip_runtime.h>
#include <math.h>

typedef __attribute__((ext_vector_type(4))) float f32x4;
typedef __attribute__((ext_vector_type(8))) __bf16 bf16x8;
typedef __attribute__((ext_vector_type(4))) __bf16 bf16x4;

// ---------------- path tables (order matches Python PATHS enumeration) ----------
__device__ __constant__ int GP_L[34]  = {0,0,0,0, 1,1,1,1,1,1,1,1,1, 2,2,2,2,2,2,2,2,2,2,2, 3,3,3,3,3,3,3,3,3,3};
__device__ __constant__ int GP_L1[34] = {0,1,2,3, 0,1,1,1,2,2,2,3,3, 0,1,1,1,2,2,2,2,3,3,3, 0,1,1,2,2,2,3,3,3,3};
__device__ __constant__ int GP_L2[34] = {0,1,2,3, 1,0,1,2,1,2,3,2,3, 2,1,2,3,0,1,2,3,1,2,3, 3,2,3,1,2,3,0,1,2,3};

// ---------------- CG coefficient init (Racah formula, double) -------------------
__device__ double dfact(int n) { double r = 1.0; for (int i = 2; i <= n; ++i) r *= (double)i; return r; }

__device__ double cg_coeff(int l1, int m1, int l2, int m2, int l3, int m3) {
  if (m3 != m1 + m2) return 0.0;
  double pref = sqrt((2.0 * l3 + 1.0) * dfact(l3 + l1 - l2) * dfact(l3 - l1 + l2)
                     * dfact(l1 + l2 - l3) / dfact(l1 + l2 + l3 + 1));
  pref *= sqrt(dfact(l3 + m3) * dfact(l3 - m3) * dfact(l1 - m1) * dfact(l1 + m1)
               * dfact(l2 - m2) * dfact(l2 + m2));
  double s = 0.0;
  for (int k = 0; k <= l1 + l2 - l3; ++k) {
    int d0 = k, d1 = l1 + l2 - l3 - k, d2 = l1 - m1 - k, d3 = l2 + m2 - k;
    int d4 = l3 - l2 + m1 + k, d5 = l3 - l1 - m2 + k;
    if (d0 < 0 || d1 < 0 || d2 < 0 || d3 < 0 || d4 < 0 || d5 < 0) continue;
    double den = dfact(d0) * dfact(d1) * dfact(d2) * dfact(d3) * dfact(d4) * dfact(d5);
    s += ((k & 1) ? -1.0 : 1.0) / den;
  }
  return pref * s;
}

__global__ void cg_init(float* __restrict__ cg) {
  int idx = blockIdx.x * 256 + threadIdx.x;
  if (idx >= 34 * 49) return;
  int gp = idx / 49, r = idx % 49;
  int m1i = r / 7, m2i = r % 7;
  int l3 = GP_L[gp], l1 = GP_L1[gp], l2 = GP_L2[gp];
  float v = 0.f;
  if (m1i <= 2 * l1 && m2i <= 2 * l2) {
    int m1 = m1i - l1, m2 = m2i - l2, m3 = m1 + m2;
    if (m3 >= -l3 && m3 <= l3) v = (float)cg_coeff(l1, m1, l2, m2, l3, m3);
  }
  cg[idx] = v;
}

// ---------------- conversions ---------------------------------------------------
__global__ __launch_bounds__(256) void cvt_u_all(
    const float* __restrict__ u0, const float* __restrict__ u1,
    const float* __restrict__ u2, const float* __restrict__ u3,
    __bf16* __restrict__ out) {
  long i = (long)blockIdx.x * 256 + threadIdx.x;  // float4 index; grid sized exactly
  const long b1 = 65536, b2 = 212992, b3 = 393216;
  const float* src; long s;
  if (i < b1)      { src = u0; s = i; }
  else if (i < b2) { src = u1; s = i - b1; }
  else if (i < b3) { src = u2; s = i - b2; }
  else             { src = u3; s = i - b3; }
  float4 v = ((const float4*)src)[s];
  bf16x4 o;
  o[0] = (__bf16)v.x; o[1] = (__bf16)v.y; o[2] = (__bf16)v.z; o[3] = (__bf16)v.w;
  ((bf16x4*)out)[i] = o;
}

__global__ void wt_cvt_all(const float* __restrict__ w0, const float* __restrict__ w1,
                           const float* __restrict__ w2, const float* __restrict__ w3,
                           __bf16* __restrict__ Wt) {
  int b = blockIdx.x;            // l*256 + j
  int l = b >> 8, j = b & 255, k = threadIdx.x;
  const float* W = (l == 0) ? w0 : (l == 1) ? w1 : (l == 2) ? w2 : w3;
  Wt[((long)l << 16) + (j << 8) + k] = (__bf16)W[(k << 8) + j];
}

// ---------------- batched bf16 MFMA GEMM (UW precompute only) -------------------
struct GemmDesc {
  const __bf16* A[4];
  const __bf16* B[4];
  void*         C[4];
  const float*  R[4];
  int start[4];
  int lmap[4];
  int Kd[4];
  int Nc[4];
};

__device__ __forceinline__ void gload_lds16(const void* g, void* l) {
  __builtin_amdgcn_global_load_lds((const __attribute__((address_space(1))) void*)g,
                                   (__attribute__((address_space(3))) void*)l, 16, 0, 0);
}

template <bool OUT_BF16, bool RESID>
__global__ __launch_bounds__(256) void gemm_batched(GemmDesc d) {
  __shared__ __bf16 As[128 * 64];
  __shared__ __bf16 Bs[128 * 64];
  const int tid = threadIdx.x;
  const int bid = blockIdx.x;
  int seg = 0;
  if (bid >= d.start[1]) seg = 1;
  if (bid >= d.start[2]) seg = 2;
  if (bid >= d.start[3]) seg = 3;
  const int l = d.lmap[seg];
  const int rel = bid - d.start[seg];
  const int Kd = d.Kd[l], Nc = d.Nc[l];
  const int nTN = Nc >> 7;
  const int tM = rel / nTN, tN = rel % nTN;

  const int lane = tid & 63, wave = tid >> 6;
  const int wm = (wave >> 1) << 6, wn = (wave & 1) << 6;
  const int lr = lane & 15, lk = (lane >> 4) << 3;

  f32x4 acc[4][4] = {};

  const int r32 = tid >> 3;
  const int sl = ((tid & 7) ^ (r32 & 7)) << 3;
  const __bf16* Ag = d.A[l] + (long)(tM * 128 + r32) * Kd + sl;
  const __bf16* Bg = d.B[l] + (long)(tN * 128 + r32) * Kd + sl;
  char* AsB = (char*)As;
  char* BsB = (char*)Bs;

  for (int kt = 0; kt < Kd; kt += 64) {
#pragma unroll
    for (int i = 0; i < 4; ++i) {
      gload_lds16(Ag + (long)i * 32 * Kd + kt, AsB + i * 4096 + tid * 16);
      gload_lds16(Bg + (long)i * 32 * Kd + kt, BsB + i * 4096 + tid * 16);
    }
    __syncthreads();

#pragma unroll
    for (int kk = 0; kk < 64; kk += 32) {
      bf16x8 af[4], bfr[4];
#pragma unroll
      for (int mi = 0; mi < 4; ++mi)
        af[mi] = *(const bf16x8*)(AsB + ((wm + mi * 16 + lr) << 7)
                                      + ((((kk + lk) << 1)) ^ ((lr & 7) << 4)));
#pragma unroll
      for (int ni = 0; ni < 4; ++ni)
        bfr[ni] = *(const bf16x8*)(BsB + ((wn + ni * 16 + lr) << 7)
                                       + ((((kk + lk) << 1)) ^ ((lr & 7) << 4)));
#pragma unroll
      for (int mi = 0; mi < 4; ++mi)
#pragma unroll
        for (int ni = 0; ni < 4; ++ni)
          acc[mi][ni] = __builtin_amdgcn_mfma_f32_16x16x32_bf16(af[mi], bfr[ni], acc[mi][ni], 0, 0, 0);
    }
    __syncthreads();
  }

  const long col0 = (long)tN * 128 + wn + lr;
  const long row0 = (long)tM * 128 + wm + ((lane >> 4) << 2);
#pragma unroll
  for (int mi = 0; mi < 4; ++mi) {
#pragma unroll
    for (int j = 0; j < 4; ++j) {
      long r = row0 + mi * 16 + j;
      long base = r * (long)Nc + col0;
#pragma unroll
      for (int ni = 0; ni < 4; ++ni) {
        long idx = base + ni * 16;
        float v = acc[mi][ni][j];
        if constexpr (RESID) v += d.R[l][idx];
        if constexpr (OUT_BF16) ((__bf16*)d.C[l])[idx] = (__bf16)v;
        else                    ((float*)d.C[l])[idx] = v;
      }
    }
  }
}

// ---------------- fused TP + GEMM, 128x128 tiles, double-buffered ----------------
struct FusedArgs {
  const float* f1[4];
  const float* f2[4];
  const float* cg;
  const __bf16* UWt;
  float* out;
};

// One TP unit: (n, 4 consecutive k). Computes all (2L+1) m's, writes swizzled LDS.
template <int L, int L1V, int L2V>
__device__ __forceinline__ void tp_pass4(
    const float* __restrict__ f1, const float* __restrict__ f2,
    long n, int kcol, const float* __restrict__ cgt,
    char* __restrict__ Adst, int row0, int kq) {
  f32x4 v1[2 * L1V + 1], v2[2 * L2V + 1];
  const float* p1 = f1 + (n * (2 * L1V + 1)) * 256 + kcol;
  const float* p2 = f2 + (n * (2 * L2V + 1)) * 256 + kcol;
#pragma unroll
  for (int a = 0; a <= 2 * L1V; ++a) v1[a] = *(const f32x4*)(p1 + a * 256);
#pragma unroll
  for (int b = 0; b <= 2 * L2V; ++b) v2[b] = *(const f32x4*)(p2 + b * 256);
  f32x4 tp[2 * L + 1];
#pragma unroll
  for (int m = 0; m <= 2 * L; ++m) { tp[m][0]=0.f; tp[m][1]=0.f; tp[m][2]=0.f; tp[m][3]=0.f; }
#pragma unroll
  for (int a = 0; a <= 2 * L1V; ++a)
#pragma unroll
    for (int b = 0; b <= 2 * L2V; ++b) {
      const int m = a + b - (L1V + L2V - L);   // constant after unroll
      if (m >= 0 && m <= 2 * L) {
        float c = cgt[a * 7 + b];
#pragma unroll
        for (int q = 0; q < 4; ++q)
          tp[m][q] = fmaf(c, v1[a][q] * v2[b][q], tp[m][q]);
      }
    }
#pragma unroll
  for (int m = 0; m <= 2 * L; ++m) {
    int row = row0 + m;
    int byte = row * 128 + ((kq << 1) ^ ((row & 7) << 4));
    bf16x4 o;
    o[0] = (__bf16)tp[m][0]; o[1] = (__bf16)tp[m][1];
    o[2] = (__bf16)tp[m][2]; o[3] = (__bf16)tp[m][3];
    *(bf16x4*)(Adst + byte) = o;
  }
}

#define TPC4(P, AA, BB)                                                         \
  case P:                                                                       \
    for (int u = tid; u < UNITS; u += 256) {                                    \
      int nl = u >> 4, kq = (u & 15) << 2;                                      \
      long n = n0 + nl; if (n > 2047) n = 2047;                                 \
      tp_pass4<L, AA, BB>(Af.f1[AA], Af.f2[BB], n, kc + kq,                     \
                          Af.cg + (GOFF + P) * 49, Adst, nl * (2 * L + 1), kq); \
    }                                                                           \
    break;

template <int L, int NB, int GOFF>
__device__ __forceinline__ void tp_step(const FusedArgs& Af, long n0, int kt,
                                        char* __restrict__ Adst, int tid) {
  constexpr int UNITS = NB * 16;
  const int p = kt >> 8, kc = kt & 255;
  if constexpr (L == 0) {
    switch (p) { TPC4(0,0,0) TPC4(1,1,1) TPC4(2,2,2) TPC4(3,3,3) default: break; }
  } else if constexpr (L == 1) {
    switch (p) { TPC4(0,0,1) TPC4(1,1,0) TPC4(2,1,1) TPC4(3,1,2) TPC4(4,2,1)
                 TPC4(5,2,2) TPC4(6,2,3) TPC4(7,3,2) TPC4(8,3,3) default: break; }
  } else if constexpr (L == 2) {
    switch (p) { TPC4(0,0,2) TPC4(1,1,1) TPC4(2,1,2) TPC4(3,1,3) TPC4(4,2,0)
                 TPC4(5,2,1) TPC4(6,2,2) TPC4(7,2,3) TPC4(8,3,1) TPC4(9,3,2)
                 TPC4(10,3,3) default: break; }
  } else {
    switch (p) { TPC4(0,0,3) TPC4(1,1,2) TPC4(2,1,3) TPC4(3,2,1) TPC4(4,2,2)
                 TPC4(5,2,3) TPC4(6,3,0) TPC4(7,3,1) TPC4(8,3,2) TPC4(9,3,3)
                 default: break; }
  }
}

__device__ __forceinline__ void mfma_step(const char* __restrict__ As,
                                          const char* __restrict__ Bs,
                                          f32x4 (&acc)[4][4], int tid) {
  const int lane = tid & 63, wave = tid >> 6;
  const int wm = (wave >> 1) << 6, wn = (wave & 1) << 6;
  const int lr = lane & 15, lkb = (lane >> 4) << 3;
  __builtin_amdgcn_s_setprio(1);
#pragma unroll
  for (int kk = 0; kk < 64; kk += 32) {
    bf16x8 af[4], bfr[4];
#pragma unroll
    for (int mi = 0; mi < 4; ++mi) {
      int row = wm + mi * 16 + lr;
      af[mi] = *(const bf16x8*)(As + row * 128 + (((kk + lkb) << 1) ^ ((row & 7) << 4)));
    }
#pragma unroll
    for (int ni = 0; ni < 4; ++ni) {
      int row = wn + ni * 16 + lr;
      bfr[ni] = *(const bf16x8*)(Bs + row * 128 + (((kk + lkb) << 1) ^ ((row & 7) << 4)));
    }
#pragma unroll
    for (int mi = 0; mi < 4; ++mi)
#pragma unroll
      for (int ni = 0; ni < 4; ++ni)
        acc[mi][ni] = __builtin_amdgcn_mfma_f32_16x16x32_bf16(af[mi], bfr[ni], acc[mi][ni], 0, 0, 0);
  }
  __builtin_amdgcn_s_setprio(0);
}

template <int L, int NB, int CIN, int GOFF>
__device__ __forceinline__ void fused_seg(
    const FusedArgs& Af, int rel, char* __restrict__ sm,
    const __bf16* __restrict__ Bmat0, float* __restrict__ Cout,
    const float* __restrict__ Resid) {
  constexpr int NT = CIN / 64;
  constexpr int VALID = NB * (2 * L + 1);
  const int tid = threadIdx.x;
  const int tile = rel >> 1, ch = rel & 1;
  const long n0 = (long)tile * NB;
  const __bf16* Bmat = Bmat0 + (long)ch * 128 * CIN;
  const int brow = tid >> 3;
  const __bf16* Bg = Bmat + (long)brow * CIN + (((tid & 7) ^ (brow & 7)) << 3);

  f32x4 acc[4][4];
#pragma unroll
  for (int i = 0; i < 4; ++i)
#pragma unroll
    for (int j = 0; j < 4; ++j) { acc[i][j][0]=0.f; acc[i][j][1]=0.f; acc[i][j][2]=0.f; acc[i][j][3]=0.f; }

  // prologue: fill buffer 0
#pragma unroll
  for (int i = 0; i < 4; ++i)
    gload_lds16(Bg + (long)i * 32 * CIN, sm + 32768 + i * 4096 + tid * 16);
  tp_step<L, NB, GOFF>(Af, n0, 0, sm, tid);
  __syncthreads();

  for (int t = 0; t < NT; ++t) {
    const int cur = t & 1;
    char* Ac = sm + cur * 16384;
    char* Bc = sm + 32768 + cur * 16384;
    if (t + 1 < NT) {
      char* An = sm + (cur ^ 1) * 16384;
      char* Bn = sm + 32768 + (cur ^ 1) * 16384;
      const int ktn = (t + 1) * 64;
#pragma unroll
      for (int i = 0; i < 4; ++i)
        gload_lds16(Bg + (long)i * 32 * CIN + ktn, Bn + i * 4096 + tid * 16);
      tp_step<L, NB, GOFF>(Af, n0, ktn, An, tid);
    }
    mfma_step(Ac, Bc, acc, tid);
    __syncthreads();
  }

  // epilogue: C = acc + resid, guarded by valid rows (pad + partial-tile)
  const int lane = tid & 63, wave = tid >> 6;
  const int wm = (wave >> 1) << 6, wn = (wave & 1) << 6;
  const int lr = lane & 15, rb = (lane >> 4) << 2;
  int rows_valid = (int)(2048 - n0) * (2 * L + 1);
  if (rows_valid > VALID) rows_valid = VALID;
  const long base_row = n0 * (2 * L + 1);
  const int colb = ch * 128 + wn + lr;
#pragma unroll
  for (int mi = 0; mi < 4; ++mi)
#pragma unroll
    for (int j = 0; j < 4; ++j) {
      int r = wm + mi * 16 + rb + j;
      if (r < rows_valid) {
        long idx = (base_row + r) * 256 + colb;
#pragma unroll
        for (int ni = 0; ni < 4; ++ni)
          Cout[idx + ni * 16] = acc[mi][ni][j] + Resid[idx + ni * 16];
      }
    }
}

// grid = 522: l2 [0,164) l3 [164,392) l1 [392,490) l0 [490,522)
__global__ __launch_bounds__(256, 2) void fused_kernel(FusedArgs Af) {
  __shared__ __align__(16) char sm[65536];
  int bid = blockIdx.x;
  {  // bijective XCD swizzle for nwg=522 = 8*65+2
    int xcd = bid & 7, j = bid >> 3;
    bid = (xcd < 2 ? xcd * 66 : 132 + (xcd - 2) * 65) + j;
  }
  if (bid < 164)
    fused_seg<2, 25, 2816, 13>(Af, bid,       sm, Af.UWt + 3328L * 256, Af.out + 2097152L, Af.f1[2]);
  else if (bid < 392)
    fused_seg<3, 18, 2560, 24>(Af, bid - 164, sm, Af.UWt + 6144L * 256, Af.out + 4718592L, Af.f1[3]);
  else if (bid < 490)
    fused_seg<1, 42, 2304, 4>(Af, bid - 392,  sm, Af.UWt + 1024L * 256, Af.out + 524288L,  Af.f1[1]);
  else
    fused_seg<0, 128, 1024, 0>(Af, bid - 490, sm, Af.UWt,               Af.out,            Af.f1[0]);
}

// ---------------- launch ---------------------------------------------------------
extern "C" void kernel_launch(void* const* d_in, const int* in_sizes, int n_in,
                              void* d_out, int out_size, void* d_ws, size_t ws_size,
                              hipStream_t stream) {
  const float* F1[4], * F2[4], * Uin[4], * Win[4];
  for (int l = 0; l < 4; ++l) {
    F1[l]  = (const float*)d_in[4 * l + 0];
    F2[l]  = (const float*)d_in[4 * l + 1];
    Uin[l] = (const float*)d_in[4 * l + 2];
    Win[l] = (const float*)d_in[4 * l + 3];
  }
  static const int cin_[4] = {1024, 2304, 2816, 2560};
  static const int cum_[4] = {0, 1024, 3328, 6144};

  char* ws = (char*)d_ws;
  float*  cg   = (float*)ws;                        // 6664 B
  __bf16* Ubf  = (__bf16*)(ws + 8192);              // 4,456,448 B
  __bf16* Wtbf = (__bf16*)(ws + 8192 + 4456448);    // 524,288 B
  __bf16* UWt  = (__bf16*)(ws + 5242880);           // 4,456,448 B

  hipLaunchKernelGGL(cg_init, dim3(7), dim3(256), 0, stream, cg);
  hipLaunchKernelGGL(cvt_u_all, dim3(2176), dim3(256), 0, stream,
                     Uin[0], Uin[1], Uin[2], Uin[3], Ubf);
  hipLaunchKernelGGL(wt_cvt_all, dim3(1024), dim3(256), 0, stream,
                     Win[0], Win[1], Win[2], Win[3], Wtbf);

  // UWt_l[j][c] = sum_k W_l[k][j] * U_l[c][k]; one batched launch.
  {
    GemmDesc d;
    int starts[4] = {0, 40, 84, 120};  // order l3,l2,l1,l0
    int lmap[4]   = {3, 2, 1, 0};
    for (int s = 0; s < 4; ++s) { d.start[s] = starts[s]; d.lmap[s] = lmap[s]; }
    for (int l = 0; l < 4; ++l) {
      d.A[l] = Wtbf + (long)l * 65536;
      d.B[l] = Ubf + (long)cum_[l] * 256;
      d.C[l] = (void*)(UWt + (long)cum_[l] * 256);
      d.R[l] = nullptr;
      d.Kd[l] = 256;
      d.Nc[l] = cin_[l];
    }
    hipLaunchKernelGGL((gemm_batched<true, false>), dim3(136), dim3(256), 0, stream, d);
  }

  // fused TP + main GEMM + residual, one launch
  {
    FusedArgs a;
    for (int l = 0; l < 4; ++l) { a.f1[l] = F1[l]; a.f2[l] = F2[l]; }
    a.cg = cg;
    a.UWt = UWt;
    a.out = (float*)d_out;
    hipLaunchKernelGGL(fused_kernel, dim3(522), dim3(256), 0, stream, a);
  }
  (void)in_sizes; (void)n_in; (void)out_size; (void)ws_size;
}

// Round 5
// 135.151 us; speedup vs baseline: 1.8453x; 1.8453x over previous
//
#include <hip/hip_runtime.h>
#include <math.h>

typedef __attribute__((ext_vector_type(4))) float f32x4;
typedef __attribute__((ext_vector_type(2))) float f32x2;
typedef __attribute__((ext_vector_type(8))) __bf16 bf16x8;
typedef __attribute__((ext_vector_type(4))) __bf16 bf16x4;
typedef __attribute__((ext_vector_type(2))) __bf16 bf16x2;

// ---------------- path tables (order matches Python PATHS enumeration) ----------
__device__ __constant__ int GP_L[34]  = {0,0,0,0, 1,1,1,1,1,1,1,1,1, 2,2,2,2,2,2,2,2,2,2,2, 3,3,3,3,3,3,3,3,3,3};
__device__ __constant__ int GP_L1[34] = {0,1,2,3, 0,1,1,1,2,2,2,3,3, 0,1,1,1,2,2,2,2,3,3,3, 0,1,1,2,2,2,3,3,3,3};
__device__ __constant__ int GP_L2[34] = {0,1,2,3, 1,0,1,2,1,2,3,2,3, 2,1,2,3,0,1,2,3,1,2,3, 3,2,3,1,2,3,0,1,2,3};

// ---------------- CG coefficient (Racah formula, double) ------------------------
__device__ double dfact(int n) { double r = 1.0; for (int i = 2; i <= n; ++i) r *= (double)i; return r; }

__device__ double cg_coeff(int l1, int m1, int l2, int m2, int l3, int m3) {
  if (m3 != m1 + m2) return 0.0;
  double pref = sqrt((2.0 * l3 + 1.0) * dfact(l3 + l1 - l2) * dfact(l3 - l1 + l2)
                     * dfact(l1 + l2 - l3) / dfact(l1 + l2 + l3 + 1));
  pref *= sqrt(dfact(l3 + m3) * dfact(l3 - m3) * dfact(l1 - m1) * dfact(l1 + m1)
               * dfact(l2 - m2) * dfact(l2 + m2));
  double s = 0.0;
  for (int k = 0; k <= l1 + l2 - l3; ++k) {
    int d0 = k, d1 = l1 + l2 - l3 - k, d2 = l1 - m1 - k, d3 = l2 + m2 - k;
    int d4 = l3 - l2 + m1 + k, d5 = l3 - l1 - m2 + k;
    if (d0 < 0 || d1 < 0 || d2 < 0 || d3 < 0 || d4 < 0 || d5 < 0) continue;
    double den = dfact(d0) * dfact(d1) * dfact(d2) * dfact(d3) * dfact(d4) * dfact(d5);
    s += ((k & 1) ? -1.0 : 1.0) / den;
  }
  return pref * s;
}

// ---------------- fused prologue: U->bf16, W^T->bf16, CG table ------------------
__global__ __launch_bounds__(256) void prep(
    const float* __restrict__ u0, const float* __restrict__ u1,
    const float* __restrict__ u2, const float* __restrict__ u3,
    const float* __restrict__ w0, const float* __restrict__ w1,
    const float* __restrict__ w2, const float* __restrict__ w3,
    __bf16* __restrict__ Ubf, __bf16* __restrict__ Wt, float* __restrict__ cg) {
  const int bid = blockIdx.x, tid = threadIdx.x;
  if (bid < 2176) {                 // U conversion, f32x4 granularity
    long i = (long)bid * 256 + tid;
    const long b1 = 65536, b2 = 212992, b3 = 393216;
    const float* src; long s;
    if (i < b1)      { src = u0; s = i; }
    else if (i < b2) { src = u1; s = i - b1; }
    else if (i < b3) { src = u2; s = i - b2; }
    else             { src = u3; s = i - b3; }
    float4 v = ((const float4*)src)[s];
    bf16x4 o;
    o[0] = (__bf16)v.x; o[1] = (__bf16)v.y; o[2] = (__bf16)v.z; o[3] = (__bf16)v.w;
    ((bf16x4*)Ubf)[i] = o;
  } else if (bid < 3200) {          // W transpose
    int b = bid - 2176;
    int l = b >> 8, j = b & 255;
    const float* W = (l == 0) ? w0 : (l == 1) ? w1 : (l == 2) ? w2 : w3;
    Wt[((long)l << 16) + (j << 8) + tid] = (__bf16)W[(tid << 8) + j];
  } else {                          // CG table
    int idx = (bid - 3200) * 256 + tid;
    if (idx < 34 * 49) {
      int gp = idx / 49, r = idx % 49;
      int m1i = r / 7, m2i = r % 7;
      int l3 = GP_L[gp], l1 = GP_L1[gp], l2 = GP_L2[gp];
      float v = 0.f;
      if (m1i <= 2 * l1 && m2i <= 2 * l2) {
        int m1 = m1i - l1, m2 = m2i - l2, m3 = m1 + m2;
        if (m3 >= -l3 && m3 <= l3) v = (float)cg_coeff(l1, m1, l2, m2, l3, m3);
      }
      cg[idx] = v;
    }
  }
}

// ---------------- batched bf16 MFMA GEMM (UW precompute only) -------------------
struct GemmDesc {
  const __bf16* A[4];
  const __bf16* B[4];
  void*         C[4];
  int start[4];
  int lmap[4];
  int Kd[4];
  int Nc[4];
};

__device__ __forceinline__ void gload_lds16(const void* g, void* l) {
  __builtin_amdgcn_global_load_lds((const __attribute__((address_space(1))) void*)g,
                                   (__attribute__((address_space(3))) void*)l, 16, 0, 0);
}

__global__ __launch_bounds__(256) void gemm_batched(GemmDesc d) {
  __shared__ __bf16 As[128 * 64];
  __shared__ __bf16 Bs[128 * 64];
  const int tid = threadIdx.x;
  const int bid = blockIdx.x;
  int seg = 0;
  if (bid >= d.start[1]) seg = 1;
  if (bid >= d.start[2]) seg = 2;
  if (bid >= d.start[3]) seg = 3;
  const int l = d.lmap[seg];
  const int rel = bid - d.start[seg];
  const int Kd = d.Kd[l], Nc = d.Nc[l];
  const int nTN = Nc >> 7;
  const int tM = rel / nTN, tN = rel % nTN;

  const int lane = tid & 63, wave = tid >> 6;
  const int wm = (wave >> 1) << 6, wn = (wave & 1) << 6;
  const int lr = lane & 15, lk = (lane >> 4) << 3;

  f32x4 acc[4][4] = {};

  const int r32 = tid >> 3;
  const int sl = ((tid & 7) ^ (r32 & 7)) << 3;
  const __bf16* Ag = d.A[l] + (long)(tM * 128 + r32) * Kd + sl;
  const __bf16* Bg = d.B[l] + (long)(tN * 128 + r32) * Kd + sl;
  char* AsB = (char*)As;
  char* BsB = (char*)Bs;

  for (int kt = 0; kt < Kd; kt += 64) {
#pragma unroll
    for (int i = 0; i < 4; ++i) {
      gload_lds16(Ag + (long)i * 32 * Kd + kt, AsB + i * 4096 + tid * 16);
      gload_lds16(Bg + (long)i * 32 * Kd + kt, BsB + i * 4096 + tid * 16);
    }
    __syncthreads();

#pragma unroll
    for (int kk = 0; kk < 64; kk += 32) {
      bf16x8 af[4], bfr[4];
#pragma unroll
      for (int mi = 0; mi < 4; ++mi)
        af[mi] = *(const bf16x8*)(AsB + ((wm + mi * 16 + lr) << 7)
                                      + ((((kk + lk) << 1)) ^ ((lr & 7) << 4)));
#pragma unroll
      for (int ni = 0; ni < 4; ++ni)
        bfr[ni] = *(const bf16x8*)(BsB + ((wn + ni * 16 + lr) << 7)
                                       + ((((kk + lk) << 1)) ^ ((lr & 7) << 4)));
#pragma unroll
      for (int mi = 0; mi < 4; ++mi)
#pragma unroll
        for (int ni = 0; ni < 4; ++ni)
          acc[mi][ni] = __builtin_amdgcn_mfma_f32_16x16x32_bf16(af[mi], bfr[ni], acc[mi][ni], 0, 0, 0);
    }
    __syncthreads();
  }

  const long col0 = (long)tN * 128 + wn + lr;
  const long row0 = (long)tM * 128 + wm + ((lane >> 4) << 2);
#pragma unroll
  for (int mi = 0; mi < 4; ++mi) {
#pragma unroll
    for (int j = 0; j < 4; ++j) {
      long r = row0 + mi * 16 + j;
      long base = r * (long)Nc + col0;
#pragma unroll
      for (int ni = 0; ni < 4; ++ni)
        ((__bf16*)d.C[l])[base + ni * 16] = (__bf16)acc[mi][ni][j];
    }
  }
}

// ---------------- TP kernel: one f-read -> all 34 paths -------------------------
#define TPW2(LV, DST, CIN, GOFF, P, L1V, L2V)                                    \
  { f32x2 tp[2 * (LV) + 1];                                                      \
    _Pragma("unroll") for (int m = 0; m <= 2 * (LV); ++m) { tp[m][0] = 0.f; tp[m][1] = 0.f; } \
    const float* cgt = cg + ((GOFF) + (P)) * 49;                                 \
    _Pragma("unroll") for (int a = 0; a <= 2 * (L1V); ++a)                       \
      _Pragma("unroll") for (int b = 0; b <= 2 * (L2V); ++b) {                   \
        const int m = a + b - ((L1V) + (L2V) - (LV));                            \
        if (m >= 0 && m <= 2 * (LV)) {                                           \
          float c = cgt[a * 7 + b];                                              \
          tp[m][0] = fmaf(c, v1[CUM[L1V] + a][0] * v2[CUM[L2V] + b][0], tp[m][0]); \
          tp[m][1] = fmaf(c, v1[CUM[L1V] + a][1] * v2[CUM[L2V] + b][1], tp[m][1]); \
        } }                                                                      \
    __bf16* o = (DST) + (n * (2 * (LV) + 1)) * (CIN) + (P) * 256 + k2;           \
    _Pragma("unroll") for (int m = 0; m <= 2 * (LV); ++m) {                      \
      bf16x2 ov; ov[0] = (__bf16)tp[m][0]; ov[1] = (__bf16)tp[m][1];             \
      *(bf16x2*)(o + (long)m * (CIN)) = ov; } }

template <int LMASK>
__global__ __launch_bounds__(256) void tp_all(
    const float* __restrict__ f10, const float* __restrict__ f11,
    const float* __restrict__ f12, const float* __restrict__ f13,
    const float* __restrict__ f20, const float* __restrict__ f21,
    const float* __restrict__ f22, const float* __restrict__ f23,
    const float* __restrict__ cg,
    __bf16* __restrict__ A0, __bf16* __restrict__ A1,
    __bf16* __restrict__ A2, __bf16* __restrict__ A3) {
  const int tid = threadIdx.x;
  const long n = (long)blockIdx.x * 2 + (tid >> 7);
  const int k2 = (tid & 127) << 1;
  constexpr int CUM[4] = {0, 1, 4, 9};
  const float* f1s[4] = {f10, f11, f12, f13};
  const float* f2s[4] = {f20, f21, f22, f23};

  f32x2 v1[16], v2[16];
#pragma unroll
  for (int l1 = 0; l1 < 4; ++l1) {
    const float* p1 = f1s[l1] + (n * (2 * l1 + 1)) * 256 + k2;
    const float* p2 = f2s[l1] + (n * (2 * l1 + 1)) * 256 + k2;
#pragma unroll
    for (int a = 0; a <= 2 * l1; ++a) {
      v1[CUM[l1] + a] = *(const f32x2*)(p1 + (long)a * 256);
      v2[CUM[l1] + a] = *(const f32x2*)(p2 + (long)a * 256);
    }
  }

  if constexpr (LMASK & 1) {
    TPW2(0, A0, 1024, 0, 0, 0, 0)  TPW2(0, A0, 1024, 0, 1, 1, 1)
    TPW2(0, A0, 1024, 0, 2, 2, 2)  TPW2(0, A0, 1024, 0, 3, 3, 3)
  }
  if constexpr (LMASK & 2) {
    TPW2(1, A1, 2304, 4, 0, 0, 1)  TPW2(1, A1, 2304, 4, 1, 1, 0)
    TPW2(1, A1, 2304, 4, 2, 1, 1)  TPW2(1, A1, 2304, 4, 3, 1, 2)
    TPW2(1, A1, 2304, 4, 4, 2, 1)  TPW2(1, A1, 2304, 4, 5, 2, 2)
    TPW2(1, A1, 2304, 4, 6, 2, 3)  TPW2(1, A1, 2304, 4, 7, 3, 2)
    TPW2(1, A1, 2304, 4, 8, 3, 3)
  }
  if constexpr (LMASK & 4) {
    TPW2(2, A2, 2816, 13, 0, 0, 2)  TPW2(2, A2, 2816, 13, 1, 1, 1)
    TPW2(2, A2, 2816, 13, 2, 1, 2)  TPW2(2, A2, 2816, 13, 3, 1, 3)
    TPW2(2, A2, 2816, 13, 4, 2, 0)  TPW2(2, A2, 2816, 13, 5, 2, 1)
    TPW2(2, A2, 2816, 13, 6, 2, 2)  TPW2(2, A2, 2816, 13, 7, 2, 3)
    TPW2(2, A2, 2816, 13, 8, 3, 1)  TPW2(2, A2, 2816, 13, 9, 3, 2)
    TPW2(2, A2, 2816, 13, 10, 3, 3)
  }
  if constexpr (LMASK & 8) {
    TPW2(3, A3, 2560, 24, 0, 0, 3)  TPW2(3, A3, 2560, 24, 1, 1, 2)
    TPW2(3, A3, 2560, 24, 2, 1, 3)  TPW2(3, A3, 2560, 24, 3, 2, 1)
    TPW2(3, A3, 2560, 24, 4, 2, 2)  TPW2(3, A3, 2560, 24, 5, 2, 3)
    TPW2(3, A3, 2560, 24, 6, 3, 0)  TPW2(3, A3, 2560, 24, 7, 3, 1)
    TPW2(3, A3, 2560, 24, 8, 3, 2)  TPW2(3, A3, 2560, 24, 9, 3, 3)
  }
}

// ---------------- main GEMM: 128x256 tile, dbuf prefetch, 512 threads -----------
struct MainDesc {
  const __bf16* A[4];
  const __bf16* B[4];
  float*        C[4];
  const float*  R[4];
  int start[4];
  int lmap[4];
  int cin4[4];
};

__global__ __launch_bounds__(512) void gemm_main(MainDesc d) {
  __shared__ __align__(16) char sm[98304];   // A dbuf 2x16KB @0, B dbuf 2x32KB @32768
  const int tid = threadIdx.x;
  int bid;
  {  // chunked XCD swizzle (gridDim.x divisible by 8)
    const int cpx = gridDim.x >> 3;
    bid = (blockIdx.x & 7) * cpx + (blockIdx.x >> 3);
  }
  int seg = 0;
  if (bid >= d.start[1]) seg = 1;
  if (bid >= d.start[2]) seg = 2;
  if (bid >= d.start[3]) seg = 3;
  const int l = d.lmap[seg];
  const int tM = bid - d.start[seg];
  const int cin = d.cin4[l];
  const int NT = cin >> 6;

  const __bf16* __restrict__ Aseg = d.A[l] + (long)tM * 128 * cin;
  const __bf16* __restrict__ Bseg = d.B[l];

  const int srow = tid >> 3;                       // 0..63
  const int sx = ((tid & 7) ^ (srow & 7)) << 3;    // swizzled k-slot (elements)

  f32x4 acc[4][4] = {};

  const int lane = tid & 63, wave = tid >> 6;
  const int wm = (wave >> 2) << 6;                 // 0 / 64
  const int wn = (wave & 3) << 6;                  // 0 / 64 / 128 / 192
  const int lr = lane & 15, lkb = (lane >> 4) << 3;

  // prologue stage buffer 0
#pragma unroll
  for (int i = 0; i < 2; ++i)
    gload_lds16(Aseg + (long)(i * 64 + srow) * cin + sx, sm + i * 8192 + tid * 16);
#pragma unroll
  for (int i = 0; i < 4; ++i)
    gload_lds16(Bseg + (long)(i * 64 + srow) * cin + sx, sm + 32768 + i * 8192 + tid * 16);
  __syncthreads();

  for (int t = 0; t < NT; ++t) {
    const int cur = t & 1;
    if (t + 1 < NT) {                              // prefetch next K-tile
      const int ktn = (t + 1) << 6;
      char* An = sm + (cur ^ 1) * 16384;
      char* Bn = sm + 32768 + (cur ^ 1) * 32768;
#pragma unroll
      for (int i = 0; i < 2; ++i)
        gload_lds16(Aseg + (long)(i * 64 + srow) * cin + ktn + sx, An + i * 8192 + tid * 16);
#pragma unroll
      for (int i = 0; i < 4; ++i)
        gload_lds16(Bseg + (long)(i * 64 + srow) * cin + ktn + sx, Bn + i * 8192 + tid * 16);
    }
    const char* Ab = sm + cur * 16384;
    const char* Bb = sm + 32768 + cur * 32768;
#pragma unroll
    for (int kk = 0; kk < 64; kk += 32) {
      bf16x8 af[4], bfr[4];
#pragma unroll
      for (int mi = 0; mi < 4; ++mi) {
        const int row = wm + mi * 16 + lr;
        af[mi] = *(const bf16x8*)(Ab + row * 128 + ((((kk + lkb) << 1)) ^ ((row & 7) << 4)));
      }
#pragma unroll
      for (int ni = 0; ni < 4; ++ni) {
        const int row = wn + ni * 16 + lr;
        bfr[ni] = *(const bf16x8*)(Bb + row * 128 + ((((kk + lkb) << 1)) ^ ((row & 7) << 4)));
      }
#pragma unroll
      for (int mi = 0; mi < 4; ++mi)
#pragma unroll
        for (int ni = 0; ni < 4; ++ni)
          acc[mi][ni] = __builtin_amdgcn_mfma_f32_16x16x32_bf16(af[mi], bfr[ni], acc[mi][ni], 0, 0, 0);
    }
    __syncthreads();
  }

  // epilogue: C = acc + resid  (M_l divisible by 128 -> no guards)
  float* __restrict__ Cout = d.C[l];
  const float* __restrict__ Resid = d.R[l];
  const int col0 = wn + lr;
  const int rb = (lane >> 4) << 2;
#pragma unroll
  for (int mi = 0; mi < 4; ++mi)
#pragma unroll
    for (int j = 0; j < 4; ++j) {
      const long row = (long)tM * 128 + wm + mi * 16 + rb + j;
      const long base = row * 256 + col0;
#pragma unroll
      for (int ni = 0; ni < 4; ++ni)
        Cout[base + ni * 16] = acc[mi][ni][j] + Resid[base + ni * 16];
    }
}

// ---------------- launch ---------------------------------------------------------
extern "C" void kernel_launch(void* const* d_in, const int* in_sizes, int n_in,
                              void* d_out, int out_size, void* d_ws, size_t ws_size,
                              hipStream_t stream) {
  const float* F1[4], * F2[4], * Uin[4], * Win[4];
  for (int l = 0; l < 4; ++l) {
    F1[l]  = (const float*)d_in[4 * l + 0];
    F2[l]  = (const float*)d_in[4 * l + 1];
    Uin[l] = (const float*)d_in[4 * l + 2];
    Win[l] = (const float*)d_in[4 * l + 3];
  }
  static const int  cin_[4]  = {1024, 2304, 2816, 2560};
  static const int  cum_[4]  = {0, 1024, 3328, 6144};
  static const long moff_[4] = {0, 524288, 2097152, 4718592};
  static const int  nTM_[4]  = {16, 48, 80, 112};
  static const long asz_[4]  = {4194304L, 28311552L, 57671680L, 73400320L}; // bytes

  char* ws = (char*)d_ws;
  float*  cg   = (float*)ws;                        // 6664 B
  __bf16* Ubf  = (__bf16*)(ws + 8192);              // 4,456,448 B
  __bf16* Wtbf = (__bf16*)(ws + 8192 + 4456448);    // 524,288 B
  __bf16* UWt  = (__bf16*)(ws + 5242880);           // 4,456,448 B
  const long ABASE = 10485760;
  const bool big = ws_size >= (size_t)(ABASE + asz_[0] + asz_[1] + asz_[2] + asz_[3]);

  __bf16* Ab[4];
  if (big) {
    long off = ABASE;
    for (int l = 0; l < 4; ++l) { Ab[l] = (__bf16*)(ws + off); off += asz_[l]; }
  } else {
    for (int l = 0; l < 4; ++l) Ab[l] = (__bf16*)(ws + ABASE);
  }

  hipLaunchKernelGGL(prep, dim3(3207), dim3(256), 0, stream,
                     Uin[0], Uin[1], Uin[2], Uin[3],
                     Win[0], Win[1], Win[2], Win[3], Ubf, Wtbf, cg);

  {  // UWt_l[j][c] = sum_k W_l[k][j] * U_l[c][k]
    GemmDesc d;
    int starts[4] = {0, 40, 84, 120};
    int lmap[4]   = {3, 2, 1, 0};
    for (int s = 0; s < 4; ++s) { d.start[s] = starts[s]; d.lmap[s] = lmap[s]; }
    for (int l = 0; l < 4; ++l) {
      d.A[l] = Wtbf + (long)l * 65536;
      d.B[l] = Ubf + (long)cum_[l] * 256;
      d.C[l] = (void*)(UWt + (long)cum_[l] * 256);
      d.Kd[l] = 256;
      d.Nc[l] = cin_[l];
    }
    hipLaunchKernelGGL(gemm_batched, dim3(136), dim3(256), 0, stream, d);
  }

  if (big) {
    hipLaunchKernelGGL((tp_all<15>), dim3(1024), dim3(256), 0, stream,
                       F1[0], F1[1], F1[2], F1[3], F2[0], F2[1], F2[2], F2[3],
                       cg, Ab[0], Ab[1], Ab[2], Ab[3]);
    MainDesc d;
    int starts[4] = {0, 112, 192, 240};   // l3(112) l2(80) l1(48) l0(16)
    int lmap[4]   = {3, 2, 1, 0};
    for (int s = 0; s < 4; ++s) { d.start[s] = starts[s]; d.lmap[s] = lmap[s]; }
    for (int l = 0; l < 4; ++l) {
      d.A[l] = Ab[l];
      d.B[l] = UWt + (long)cum_[l] * 256;
      d.C[l] = (float*)d_out + moff_[l];
      d.R[l] = F1[l];
      d.cin4[l] = cin_[l];
    }
    hipLaunchKernelGGL(gemm_main, dim3(256), dim3(512), 0, stream, d);
  } else {
    for (int l = 0; l < 4; ++l) {
      switch (l) {
        case 0: hipLaunchKernelGGL((tp_all<1>), dim3(1024), dim3(256), 0, stream,
                  F1[0],F1[1],F1[2],F1[3], F2[0],F2[1],F2[2],F2[3], cg,
                  Ab[0],Ab[1],Ab[2],Ab[3]); break;
        case 1: hipLaunchKernelGGL((tp_all<2>), dim3(1024), dim3(256), 0, stream,
                  F1[0],F1[1],F1[2],F1[3], F2[0],F2[1],F2[2],F2[3], cg,
                  Ab[0],Ab[1],Ab[2],Ab[3]); break;
        case 2: hipLaunchKernelGGL((tp_all<4>), dim3(1024), dim3(256), 0, stream,
                  F1[0],F1[1],F1[2],F1[3], F2[0],F2[1],F2[2],F2[3], cg,
                  Ab[0],Ab[1],Ab[2],Ab[3]); break;
        case 3: hipLaunchKernelGGL((tp_all<8>), dim3(1024), dim3(256), 0, stream,
                  F1[0],F1[1],F1[2],F1[3], F2[0],F2[1],F2[2],F2[3], cg,
                  Ab[0],Ab[1],Ab[2],Ab[3]); break;
      }
      MainDesc d;
      for (int s = 0; s < 4; ++s) {
        d.start[s] = (s == 0) ? 0 : 0x7fffffff;
        d.lmap[s] = l;
      }
      for (int ll = 0; ll < 4; ++ll) {
        d.A[ll] = Ab[l];
        d.B[ll] = UWt + (long)cum_[l] * 256;
        d.C[ll] = (float*)d_out + moff_[l];
        d.R[ll] = F1[l];
        d.cin4[ll] = cin_[l];
      }
      hipLaunchKernelGGL(gemm_main, dim3(nTM_[l]), dim3(512), 0, stream, d);
    }
  }
  (void)in_sizes; (void)n_in; (void)out_size; (void)ws_size;
}